// Round 6
// baseline (399.562 us; speedup 1.0000x reference)
//
#include <hip/hip_runtime.h>
#include <hip/hip_cooperative_groups.h>
#include <math.h>

namespace cg = cooperative_groups;

typedef float f32x4 __attribute__((ext_vector_type(4)));
typedef __bf16 bf16x8 __attribute__((ext_vector_type(8)));
typedef __bf16 bf16x4 __attribute__((ext_vector_type(4)));

// ---------------------------------------------------------------------------
// JAX threefry2x32 (exact port) + dropout mask replication.
// ---------------------------------------------------------------------------
#define PARTITIONABLE 1

__device__ __forceinline__ void threefry2x32(unsigned k0, unsigned k1,
                                             unsigned c0, unsigned c1,
                                             unsigned &o0, unsigned &o1) {
  unsigned ks2 = k0 ^ k1 ^ 0x1BD11BDAu;
  unsigned x0 = c0 + k0, x1 = c1 + k1;
#define ROTL(v, n) (((v) << (n)) | ((v) >> (32 - (n))))
#define R4(a, b, c, d)                                   \
  { x0 += x1; x1 = ROTL(x1, a); x1 ^= x0;                \
    x0 += x1; x1 = ROTL(x1, b); x1 ^= x0;                \
    x0 += x1; x1 = ROTL(x1, c); x1 ^= x0;                \
    x0 += x1; x1 = ROTL(x1, d); x1 ^= x0; }
  R4(13, 15, 26, 6);  x0 += k1;  x1 += ks2 + 1u;
  R4(17, 29, 16, 24); x0 += ks2; x1 += k0 + 2u;
  R4(13, 15, 26, 6);  x0 += k0;  x1 += k1 + 3u;
  R4(17, 29, 16, 24); x0 += k1;  x1 += ks2 + 4u;
  R4(13, 15, 26, 6);  x0 += ks2; x1 += k0 + 5u;
  o0 = x0; o1 = x1;
#undef R4
#undef ROTL
}

__device__ __forceinline__ float dropout_scale(int layer, unsigned i) {
#if PARTITIONABLE
  unsigned d0, d1, y0, y1;
  threefry2x32(0u, 7u, 0u, (unsigned)layer, d0, d1);
  threefry2x32(d0, d1, 0u, i, y0, y1);
  unsigned bits = y0 ^ y1;
#else
  unsigned a0, b0, a1, b1v, y0, y1;
  threefry2x32(0u, 7u, 0u, 2u, a0, b0);
  threefry2x32(0u, 7u, 1u, 3u, a1, b1v);
  unsigned k0 = (layer == 0) ? a0 : b0;
  unsigned k1 = (layer == 0) ? a1 : b1v;
  const unsigned half = 16384u;
  unsigned lane = (i < half) ? 0u : 1u;
  unsigned j = lane ? (i - half) : i;
  threefry2x32(k0, k1, j, j + half, y0, y1);
  unsigned bits = lane ? y1 : y0;
#endif
  return (bits & 0x80000000u) ? 0.0f : 2.0f;
}

__device__ __forceinline__ float sigmoidf(float x) {
  return 1.0f / (1.0f + expf(-x));
}

// ---------------------------------------------------------------------------
struct MegaArgs {
  const float *enc, *mels, *prev, *h1, *c1, *h2, *c2;
  const float *Wp1, *bp1, *Wp2, *bp2, *Wq, *Wk, *bk, *va, *bsc;
  const float *Wx1, *Wh1, *bl1, *Wx2, *Wh2, *bl2, *Wpj, *bpj;
  float *mel, *stops, *aligno, *h1n, *c1n, *h2n, *c2n;
  float *q_ws, *sc_ws, *rnn_in, *parts;
  __bf16 *WkT;
};

// ---------------------------------------------------------------------------
// zgemm phase (512-thread blocks): 128 rows x 128 cols, K-quarter.
// bid: cb=bid&31 (col-block of 128), zp=bid>>5 (seg=zp>>2, kq=zp&3).
// A staged to LDS bf16 swizzled; W frags loaded directly from global.
// ---------------------------------------------------------------------------
__device__ __forceinline__ void zgemm_phase512(
    const float* __restrict__ A0, int K0, const float* __restrict__ W0,
    const float* __restrict__ A1, int K1, const float* __restrict__ W1,
    float* __restrict__ parts, int bid, int tid, char* smem) {
  int cb = bid & 31;
  int zp = bid >> 5;
  int seg = zp >> 2, kq = zp & 3;
  const float* Ap = seg ? A1 : A0;
  const float* W = seg ? W1 : W0;
  int K = seg ? K1 : K0;
  int kc = K >> 2;           // 192 or 256
  int kbeg = kq * kc, kend = kbeg + kc;
  int lane = tid & 63, wid = tid >> 6;
  int wr = wid >> 2, wc = wid & 3;
  __bf16* Ab = (__bf16*)smem;

  f32x4 acc[4][2];
#pragma unroll
  for (int i = 0; i < 4; ++i)
#pragma unroll
    for (int j = 0; j < 2; ++j) acc[i][j] = (f32x4){0.f, 0.f, 0.f, 0.f};

  int n_base = cb * 128 + wc * 32 + (lane & 15);
  int koct = (lane >> 4) * 8;
  int er = tid >> 4, ek4 = (tid & 15) * 4;

  for (int k0 = kbeg; k0 < kend; k0 += 64) {
    __syncthreads();
#pragma unroll
    for (int p = 0; p < 4; ++p) {
      int row = er + p * 32;
      const float4 v = *reinterpret_cast<const float4*>(
          &Ap[(size_t)row * K + k0 + ek4]);
      bf16x4 w;
      w[0] = (__bf16)v.x; w[1] = (__bf16)v.y;
      w[2] = (__bf16)v.z; w[3] = (__bf16)v.w;
      *reinterpret_cast<bf16x4*>(&Ab[row * 64 + (ek4 ^ ((row & 7) << 3))]) = w;
    }
    __syncthreads();
#pragma unroll
    for (int kk = 0; kk < 64; kk += 32) {
      bf16x8 wfr[2];
#pragma unroll
      for (int j = 0; j < 2; ++j) {
        const float* wq = W + (size_t)(k0 + kk + koct) * 4096 + n_base + j * 16;
        bf16x8 bv;
#pragma unroll
        for (int e = 0; e < 8; ++e) bv[e] = (__bf16)wq[(size_t)e * 4096];
        wfr[j] = bv;
      }
      int kl = kk + koct;
#pragma unroll
      for (int i = 0; i < 4; ++i) {
        int t = wr * 64 + i * 16 + (lane & 15);
        bf16x8 af = *reinterpret_cast<const bf16x8*>(
            &Ab[t * 64 + (kl ^ ((t & 7) << 3))]);
        acc[i][0] = __builtin_amdgcn_mfma_f32_16x16x32_bf16(af, wfr[0], acc[i][0], 0, 0, 0);
        acc[i][1] = __builtin_amdgcn_mfma_f32_16x16x32_bf16(af, wfr[1], acc[i][1], 0, 0, 0);
      }
    }
  }
  float* outp = parts + (size_t)zp * (128 * 4096);
#pragma unroll
  for (int i = 0; i < 4; ++i)
#pragma unroll
    for (int j = 0; j < 2; ++j)
#pragma unroll
      for (int r = 0; r < 4; ++r) {
        int row = wr * 64 + i * 16 + ((lane >> 4) << 2) + r;
        int col = cb * 128 + wc * 32 + j * 16 + (lane & 15);
        outp[(size_t)row * 4096 + col] = acc[i][j][r];
      }
}

__device__ __forceinline__ void gate_phase512(
    const float* __restrict__ parts, const float* __restrict__ bias,
    const float* __restrict__ c_prev, float* __restrict__ h_out,
    float* __restrict__ c_out, int bid, int tid) {
  int idx = bid * 512 + tid;  // exactly 131072 over 256 blocks
  int b = idx >> 10, j = idx & 1023;
  float zv[4];
#pragma unroll
  for (int g = 0; g < 4; ++g) {
    size_t off = (size_t)b * 4096 + g * 1024 + j;
    float s = bias[g * 1024 + j];
#pragma unroll
    for (int p = 0; p < 8; ++p) s += parts[(size_t)p * (128 * 4096) + off];
    zv[g] = s;
  }
  float ig = sigmoidf(zv[0]);
  float fg = sigmoidf(zv[1]);
  float gg = tanhf(zv[2]);
  float og = sigmoidf(zv[3]);
  float cn = fg * c_prev[idx] + ig * gg;
  float hn = og * tanhf(cn);
  h_out[idx] = hn;
  c_out[idx] = cn;
}

// ---------------------------------------------------------------------------
// Mega kernel: 256 blocks x 512 threads (1 block/CU guaranteed), grid syncs
// between phases.
// ---------------------------------------------------------------------------
__global__ __launch_bounds__(512, 2) void mega_kernel(MegaArgs A) {
  cg::grid_group grid = cg::this_grid();
  __shared__ __align__(16) char smem[35328];
  const int bid = blockIdx.x;
  const int tid = threadIdx.x;
  const int lane = tid & 63, wid = tid >> 6;

  // ---------------- Phase A: prenet (bid<128) + WkT prep (bid 128..159)
  if (bid < 128) {
    int b = bid, j = tid;
    float* mel_s = (float*)smem;              // 80 f
    float* x1_s  = (float*)(smem + 512);      // 256 f
    float* x2_s  = (float*)(smem + 1664);     // 256 f
    if (j < 80) mel_s[j] = A.mels[b * 80 + j];
    if (j < 256) {  // zero att slice for atomicAdd accumulation
      A.rnn_in[(size_t)b * 768 + 256 + j] = 0.0f;
      A.rnn_in[(size_t)b * 768 + 512 + j] = 0.0f;
    }
    __syncthreads();
    if (j < 256) {
      float s = A.bp1[j];
      for (int m = 0; m < 80; ++m) s = fmaf(mel_s[m], A.Wp1[m * 256 + j], s);
      s = fmaxf(s, 0.0f) * dropout_scale(0, (unsigned)(b * 256 + j));
      x1_s[j] = s;
    }
    __syncthreads();
    if (j < 256) {
      float s2 = A.bp2[j];
      for (int m = 0; m < 256; ++m) s2 = fmaf(x1_s[m], A.Wp2[m * 256 + j], s2);
      s2 = fmaxf(s2, 0.0f) * dropout_scale(1, (unsigned)(b * 256 + j));
      x2_s[j] = s2;
      A.rnn_in[(size_t)b * 768 + j] = s2;
    }
    __syncthreads();
    if (j < 128) {
      float sq = 0.0f;
      for (int m = 0; m < 256; ++m) sq = fmaf(x2_s[m], A.Wq[m * 128 + j], sq);
      A.q_ws[b * 128 + j] = sq;
    }
  } else {
    int gid = (bid - 128) * 512 + tid;
    if (gid < 16384) {
      int a = gid & 127;
      int k4 = (gid >> 7) * 4;
      bf16x4 w;
      for (int i = 0; i < 4; ++i)
        w[i] = (__bf16)A.Wk[(size_t)(k4 + i) * 128 + a];
      *reinterpret_cast<bf16x4*>(&A.WkT[(size_t)a * 512 + k4]) = w;
    }
  }
  grid.sync();

  // ---------------- Phase B: score. 512 tiles of 128t x 128a; 2 per block.
  {
    __bf16* Eb = (__bf16*)smem;
    __bf16* Wb = (__bf16*)(smem + 16384);
    float (*red)[4] = (float (*)[4])(smem + 32768);  // 128 x 4
    int wr = wid >> 2, wc = wid & 3;  // 2 x 4 wave grid: 64 rows x 32 cols
    int er = tid >> 4, ek4 = (tid & 15) * 4;
    int wrw = tid >> 3, wkc = (tid & 7) * 8;

    for (int pass = 0; pass < 2; ++pass) {
      int tile = bid * 2 + pass;
      int b = tile >> 2, t0 = (tile & 3) * 128;

      f32x4 acc[4][2];
#pragma unroll
      for (int i = 0; i < 4; ++i)
#pragma unroll
        for (int j = 0; j < 2; ++j) acc[i][j] = (f32x4){0.f, 0.f, 0.f, 0.f};

      float qv[2], vav[2];
#pragma unroll
      for (int j = 0; j < 2; ++j) {
        int a = wc * 32 + j * 16 + (lane & 15);
        qv[j] = A.q_ws[b * 128 + a] + A.bk[a];
        vav[j] = A.va[a];
      }

      for (int k0 = 0; k0 < 512; k0 += 64) {
        __syncthreads();
#pragma unroll
        for (int p = 0; p < 4; ++p) {
          int t = er + p * 32;
          const float4 v = *reinterpret_cast<const float4*>(
              &A.enc[((size_t)(b * 512 + t0 + t)) * 512 + k0 + ek4]);
          bf16x4 w;
          w[0] = (__bf16)v.x; w[1] = (__bf16)v.y;
          w[2] = (__bf16)v.z; w[3] = (__bf16)v.w;
          *reinterpret_cast<bf16x4*>(&Eb[t * 64 + (ek4 ^ ((t & 7) << 3))]) = w;
        }
#pragma unroll
        for (int p = 0; p < 2; ++p) {
          int a2 = wrw + p * 64;
          uint4 v = *reinterpret_cast<const uint4*>(
              &A.WkT[(size_t)a2 * 512 + k0 + wkc]);
          *reinterpret_cast<uint4*>(&Wb[a2 * 64 + (wkc ^ ((a2 & 7) << 3))]) = v;
        }
        __syncthreads();
#pragma unroll
        for (int kk = 0; kk < 64; kk += 32) {
          int kl = kk + (lane >> 4) * 8;
          bf16x8 bfr[2];
#pragma unroll
          for (int j = 0; j < 2; ++j) {
            int a = wc * 32 + j * 16 + (lane & 15);
            bfr[j] = *reinterpret_cast<const bf16x8*>(
                &Wb[a * 64 + (kl ^ ((a & 7) << 3))]);
          }
#pragma unroll
          for (int i = 0; i < 4; ++i) {
            int t = wr * 64 + i * 16 + (lane & 15);
            bf16x8 af = *reinterpret_cast<const bf16x8*>(
                &Eb[t * 64 + (kl ^ ((t & 7) << 3))]);
            acc[i][0] = __builtin_amdgcn_mfma_f32_16x16x32_bf16(af, bfr[0], acc[i][0], 0, 0, 0);
            acc[i][1] = __builtin_amdgcn_mfma_f32_16x16x32_bf16(af, bfr[1], acc[i][1], 0, 0, 0);
          }
        }
      }
#pragma unroll
      for (int i = 0; i < 4; ++i) {
#pragma unroll
        for (int r = 0; r < 4; ++r) {
          float s = tanhf(qv[0] + acc[i][0][r]) * vav[0] +
                    tanhf(qv[1] + acc[i][1][r]) * vav[1];
          s += __shfl_xor(s, 1, 64);
          s += __shfl_xor(s, 2, 64);
          s += __shfl_xor(s, 4, 64);
          s += __shfl_xor(s, 8, 64);
          if ((lane & 15) == 0)
            red[wr * 64 + i * 16 + (lane >> 4) * 4 + r][wc] = s;
        }
      }
      __syncthreads();
      if (tid < 128)
        A.sc_ws[b * 512 + t0 + tid] =
            red[tid][0] + red[tid][1] + red[tid][2] + red[tid][3] + A.bsc[0];
      __syncthreads();
    }
  }
  grid.sync();

  // ---------------- Phase C: monotonic scan (bid<128; 512 threads = T)
  if (bid < 128) {
    int b = bid, t = tid;
    float* s = (float*)smem;  // 512 f
    float p = sigmoidf(A.sc_ws[b * 512 + t]);
    float omp = 1.0f - p;
    s[t] = omp;
    __syncthreads();
    for (int off = 1; off < 512; off <<= 1) {
      float v = (t >= off) ? s[t - off] : 1.0f;
      __syncthreads();
      if (t >= off) s[t] *= v;
      __syncthreads();
    }
    float cp_excl = (t == 0) ? 1.0f : s[t - 1];
    __syncthreads();
    float denom = fminf(fmaxf(cp_excl, 1e-10f), 1.0f);
    float r = A.prev[b * 512 + t] / denom;
    s[t] = r;
    __syncthreads();
    for (int off = 1; off < 512; off <<= 1) {
      float v = (t >= off) ? s[t - off] : 0.0f;
      __syncthreads();
      if (t >= off) s[t] += v;
      __syncthreads();
    }
    A.aligno[b * 512 + t] = p * cp_excl * s[t];
  }
  grid.sync();

  // ---------------- Phase D: attention (1024 tasks; 4/block; v = tid)
  {
    float* al = (float*)smem;            // 64 f
    int* flagp = (int*)(smem + 256);
    for (int i = 0; i < 4; ++i) {
      int task = bid * 4 + i;            // 0..1023
      int b = task >> 3;
      int tc = task & 7;
      __syncthreads();
      if (tid == 0) *flagp = 0;
      __syncthreads();
      if (tid < 64) {
        float a = A.aligno[b * 512 + tc * 64 + tid];
        al[tid] = a;
        if (a != 0.0f) *flagp = 1;
      }
      __syncthreads();
      if (*flagp) {
        float acc = 0.0f;
        for (int tt = 0; tt < 64; ++tt) {
          float a = al[tt];
          if (a != 0.0f)
            acc = fmaf(a, A.enc[((size_t)(b * 512 + tc * 64 + tt)) * 512 + tid], acc);
        }
        atomicAdd(&A.rnn_in[(size_t)b * 768 + 256 + tid], acc);
      }
    }
  }
  grid.sync();

  // ---------------- Phase E: LSTM1 GEMM
  zgemm_phase512(A.rnn_in, 768, A.Wx1, A.h1, 1024, A.Wh1, A.parts, bid, tid, smem);
  grid.sync();

  // ---------------- Phase F: gate1
  gate_phase512(A.parts, A.bl1, A.c1, A.h1n, A.c1n, bid, tid);
  grid.sync();

  // ---------------- Phase G: LSTM2 GEMM
  zgemm_phase512(A.h1n, 1024, A.Wx2, A.h2, 1024, A.Wh2, A.parts, bid, tid, smem);
  grid.sync();

  // ---------------- Phase H: gate2
  gate_phase512(A.parts, A.bl2, A.c2, A.h2n, A.c2n, bid, tid);
  grid.sync();

  // ---------------- Phase I: projection (bid<128)
  if (bid < 128) {
    int b = bid;
    float* row = (float*)smem;  // 1536 f
    for (int i = tid; i < 1536; i += 512)
      row[i] = (i < 1024) ? A.h2n[(size_t)b * 1024 + i]
                          : A.rnn_in[(size_t)b * 768 + 256 + (i - 1024)];
    __syncthreads();
    if (tid < 81) {
      float s = A.bpj[tid];
      for (int m = 0; m < 1536; ++m) s = fmaf(row[m], A.Wpj[m * 81 + tid], s);
      if (tid < 80) A.mel[b * 80 + tid] = s;
      else A.stops[b] = s;
    }
  }
}

// ===========================================================================
// FALLBACK PATH (proven round-4 kernels) — used only if cooperative launch
// is rejected at runtime.
// ===========================================================================
__global__ __launch_bounds__(256) void fb_prenet_kernel(
    const float* __restrict__ mels, const float* __restrict__ W1,
    const float* __restrict__ b1, const float* __restrict__ W2,
    const float* __restrict__ b2, const float* __restrict__ Wq,
    const float* __restrict__ Wk, __bf16* __restrict__ WkT,
    float* __restrict__ rnn_in, float* __restrict__ q_out) {
  int blk = blockIdx.x;
  int j = threadIdx.x;
  if (blk >= 128) {
    int gid = (blk - 128) * 256 + j;
    int a = gid & 127;
    int k4 = (gid >> 7) * 4;
    bf16x4 w;
    for (int i = 0; i < 4; ++i) w[i] = (__bf16)Wk[(size_t)(k4 + i) * 128 + a];
    *reinterpret_cast<bf16x4*>(&WkT[(size_t)a * 512 + k4]) = w;
    return;
  }
  int b = blk;
  __shared__ float mel_s[80];
  __shared__ float x1_s[256];
  __shared__ float x2_s[256];
  if (j < 80) mel_s[j] = mels[b * 80 + j];
  rnn_in[(size_t)b * 768 + 256 + j] = 0.0f;
  rnn_in[(size_t)b * 768 + 512 + j] = 0.0f;
  __syncthreads();
  float s = b1[j];
  for (int m = 0; m < 80; ++m) s = fmaf(mel_s[m], W1[m * 256 + j], s);
  s = fmaxf(s, 0.0f) * dropout_scale(0, (unsigned)(b * 256 + j));
  x1_s[j] = s;
  __syncthreads();
  float s2 = b2[j];
  for (int m = 0; m < 256; ++m) s2 = fmaf(x1_s[m], W2[m * 256 + j], s2);
  s2 = fmaxf(s2, 0.0f) * dropout_scale(1, (unsigned)(b * 256 + j));
  x2_s[j] = s2;
  rnn_in[(size_t)b * 768 + j] = s2;
  __syncthreads();
  if (j < 128) {
    float sq = 0.0f;
    for (int m = 0; m < 256; ++m) sq = fmaf(x2_s[m], Wq[m * 128 + j], sq);
    q_out[b * 128 + j] = sq;
  }
}

__global__ __launch_bounds__(256) void fb_score_kernel(
    const float* __restrict__ enc, const __bf16* __restrict__ WkT,
    const float* __restrict__ bk, const float* __restrict__ q,
    const float* __restrict__ va_g, const float* __restrict__ bscore,
    float* __restrict__ score) {
  int b = blockIdx.y;
  int t0 = blockIdx.x * 128;
  int tid = threadIdx.x;
  int lane = tid & 63, wid = tid >> 6;
  int wr = wid >> 1, wc = wid & 1;
  __shared__ __align__(16) __bf16 Eb[128 * 64];
  __shared__ __align__(16) __bf16 Wb[128 * 64];
  __shared__ float red[128][4];
  f32x4 acc[4][4];
#pragma unroll
  for (int i = 0; i < 4; ++i)
#pragma unroll
    for (int j = 0; j < 4; ++j) acc[i][j] = (f32x4){0.f, 0.f, 0.f, 0.f};
  float qv[4], vav[4];
#pragma unroll
  for (int j = 0; j < 4; ++j) {
    int a = wc * 64 + j * 16 + (lane & 15);
    qv[j] = q[b * 128 + a] + bk[a];
    vav[j] = va_g[a];
  }
  int er = tid >> 4, ek4 = (tid & 15) * 4;
  int wrw = tid >> 3, wkc = (tid & 7) * 8;
  for (int k0 = 0; k0 < 512; k0 += 64) {
    __syncthreads();
#pragma unroll
    for (int p = 0; p < 8; ++p) {
      int t = er + p * 16;
      const float4 v = *reinterpret_cast<const float4*>(
          &enc[((size_t)(b * 512 + t0 + t)) * 512 + k0 + ek4]);
      bf16x4 w;
      w[0] = (__bf16)v.x; w[1] = (__bf16)v.y;
      w[2] = (__bf16)v.z; w[3] = (__bf16)v.w;
      *reinterpret_cast<bf16x4*>(&Eb[t * 64 + (ek4 ^ ((t & 7) << 3))]) = w;
    }
#pragma unroll
    for (int p = 0; p < 4; ++p) {
      int a = wrw + p * 32;
      uint4 v = *reinterpret_cast<const uint4*>(&WkT[(size_t)a * 512 + k0 + wkc]);
      *reinterpret_cast<uint4*>(&Wb[a * 64 + (wkc ^ ((a & 7) << 3))]) = v;
    }
    __syncthreads();
#pragma unroll
    for (int kk = 0; kk < 64; kk += 32) {
      bf16x8 af[4], bfr[4];
      int kl = kk + (lane >> 4) * 8;
#pragma unroll
      for (int i = 0; i < 4; ++i) {
        int t = wr * 64 + i * 16 + (lane & 15);
        af[i] = *reinterpret_cast<const bf16x8*>(&Eb[t * 64 + (kl ^ ((t & 7) << 3))]);
      }
#pragma unroll
      for (int j = 0; j < 4; ++j) {
        int a = wc * 64 + j * 16 + (lane & 15);
        bfr[j] = *reinterpret_cast<const bf16x8*>(&Wb[a * 64 + (kl ^ ((a & 7) << 3))]);
      }
#pragma unroll
      for (int i = 0; i < 4; ++i)
#pragma unroll
        for (int j = 0; j < 4; ++j)
          acc[i][j] = __builtin_amdgcn_mfma_f32_16x16x32_bf16(
              af[i], bfr[j], acc[i][j], 0, 0, 0);
    }
  }
#pragma unroll
  for (int i = 0; i < 4; ++i) {
#pragma unroll
    for (int r = 0; r < 4; ++r) {
      float s = 0.0f;
#pragma unroll
      for (int j = 0; j < 4; ++j) s += tanhf(qv[j] + acc[i][j][r]) * vav[j];
      s += __shfl_xor(s, 1, 64);
      s += __shfl_xor(s, 2, 64);
      s += __shfl_xor(s, 4, 64);
      s += __shfl_xor(s, 8, 64);
      if ((lane & 15) == 0)
        red[wr * 64 + i * 16 + (lane >> 4) * 4 + r][wc] = s;
    }
  }
  __syncthreads();
  if (tid < 128)
    score[b * 512 + t0 + tid] = red[tid][0] + red[tid][1] + bscore[0];
}

__global__ __launch_bounds__(512) void fb_scan_kernel(
    const float* __restrict__ score, const float* __restrict__ prev_align,
    float* __restrict__ align_out) {
  int b = blockIdx.x, t = threadIdx.x;
  __shared__ float s[512];
  float p = sigmoidf(score[b * 512 + t]);
  float omp = 1.0f - p;
  s[t] = omp;
  __syncthreads();
  for (int off = 1; off < 512; off <<= 1) {
    float v = (t >= off) ? s[t - off] : 1.0f;
    __syncthreads();
    if (t >= off) s[t] *= v;
    __syncthreads();
  }
  float cp_excl = (t == 0) ? 1.0f : s[t - 1];
  __syncthreads();
  float denom = fminf(fmaxf(cp_excl, 1e-10f), 1.0f);
  float r = prev_align[b * 512 + t] / denom;
  s[t] = r;
  __syncthreads();
  for (int off = 1; off < 512; off <<= 1) {
    float v = (t >= off) ? s[t - off] : 0.0f;
    __syncthreads();
    if (t >= off) s[t] += v;
    __syncthreads();
  }
  align_out[b * 512 + t] = p * cp_excl * s[t];
}

__global__ __launch_bounds__(256) void fb_att_part_kernel(
    const float* __restrict__ align, const float* __restrict__ enc,
    float* __restrict__ rnn_in) {
  int tc = blockIdx.x;
  int vt = blockIdx.y;
  int b = blockIdx.z;
  int tid = threadIdx.x;
  int v = vt * 256 + tid;
  __shared__ float al[64];
  __shared__ int flag;
  if (tid == 0) flag = 0;
  __syncthreads();
  if (tid < 64) {
    float a = align[b * 512 + tc * 64 + tid];
    al[tid] = a;
    if (a != 0.0f) flag = 1;
  }
  __syncthreads();
  if (!flag) return;
  float acc = 0.0f;
  for (int tt = 0; tt < 64; ++tt) {
    float a = al[tt];
    if (a != 0.0f)
      acc = fmaf(a, enc[((size_t)(b * 512 + tc * 64 + tt)) * 512 + v], acc);
  }
  atomicAdd(&rnn_in[(size_t)b * 768 + 256 + v], acc);
}

__global__ __launch_bounds__(256) void fb_zgemm_kernel(
    const float* __restrict__ A0, int K0, const float* __restrict__ W0,
    const float* __restrict__ A1, int K1, const float* __restrict__ W1,
    float* __restrict__ parts) {
  int cb = blockIdx.x;   // 0..63
  int zp = blockIdx.y;   // 0..3
  int seg = zp >> 1, kh = zp & 1;
  const float* Ap = seg ? A1 : A0;
  const float* W = seg ? W1 : W0;
  int K = seg ? K1 : K0;
  int kc = K >> 1;
  int kbeg = kh * kc;
  int nch = kc >> 6;
  int tid = threadIdx.x;
  int lane = tid & 63, wid = tid >> 6;
  int wr = wid >> 1, wc = wid & 1;
  __shared__ __align__(16) __bf16 Ab[128 * 64];
  f32x4 acc[4][2];
#pragma unroll
  for (int i = 0; i < 4; ++i)
#pragma unroll
    for (int j = 0; j < 2; ++j) acc[i][j] = (f32x4){0.f, 0.f, 0.f, 0.f};
  int n_base = cb * 64 + wc * 32 + (lane & 15);
  int koct = (lane >> 4) * 8;
  int ar = tid >> 4, ak4 = (tid & 15) * 4;
  for (int it = 0; it < nch; ++it) {
    int k0 = kbeg + it * 64;
    __syncthreads();
#pragma unroll
    for (int p = 0; p < 8; ++p) {
      int row = ar + p * 16;
      const float4 v = *reinterpret_cast<const float4*>(
          &Ap[(size_t)row * K + k0 + ak4]);
      bf16x4 w;
      w[0] = (__bf16)v.x; w[1] = (__bf16)v.y;
      w[2] = (__bf16)v.z; w[3] = (__bf16)v.w;
      *reinterpret_cast<bf16x4*>(&Ab[row * 64 + (ak4 ^ ((row & 7) << 3))]) = w;
    }
    __syncthreads();
#pragma unroll
    for (int kk = 0; kk < 64; kk += 32) {
      bf16x8 wfr[2];
#pragma unroll
      for (int jf = 0; jf < 2; ++jf) {
        const float* wq = W + (size_t)(k0 + kk + koct) * 4096 + n_base + jf * 16;
        bf16x8 bv;
#pragma unroll
        for (int j = 0; j < 8; ++j) bv[j] = (__bf16)wq[(size_t)j * 4096];
        wfr[jf] = bv;
      }
#pragma unroll
      for (int i = 0; i < 4; ++i) {
        int t = wr * 64 + i * 16 + (lane & 15);
        bf16x8 af = *reinterpret_cast<const bf16x8*>(
            &Ab[t * 64 + ((kk + koct) ^ ((t & 7) << 3))]);
        acc[i][0] = __builtin_amdgcn_mfma_f32_16x16x32_bf16(af, wfr[0], acc[i][0], 0, 0, 0);
        acc[i][1] = __builtin_amdgcn_mfma_f32_16x16x32_bf16(af, wfr[1], acc[i][1], 0, 0, 0);
      }
    }
  }
  float* outp = parts + (size_t)zp * (128 * 4096);
#pragma unroll
  for (int i = 0; i < 4; ++i)
#pragma unroll
    for (int jf = 0; jf < 2; ++jf)
#pragma unroll
      for (int r = 0; r < 4; ++r) {
        int row = wr * 64 + i * 16 + ((lane >> 4) << 2) + r;
        int col = cb * 64 + wc * 32 + jf * 16 + (lane & 15);
        outp[(size_t)row * 4096 + col] = acc[i][jf][r];
      }
}

__global__ __launch_bounds__(256) void fb_gate_kernel(
    const float* __restrict__ parts, const float* __restrict__ bias,
    const float* __restrict__ c_prev, float* __restrict__ h_out,
    float* __restrict__ c_out) {
  int idx = blockIdx.x * 256 + threadIdx.x;
  int b = idx >> 10, j = idx & 1023;
  float zv[4];
  for (int g = 0; g < 4; ++g) {
    size_t off = (size_t)b * 4096 + g * 1024 + j;
    float s = bias[g * 1024 + j];
    for (int p = 0; p < 4; ++p) s += parts[(size_t)p * (128 * 4096) + off];
    zv[g] = s;
  }
  float ig = sigmoidf(zv[0]);
  float fg = sigmoidf(zv[1]);
  float gg = tanhf(zv[2]);
  float og = sigmoidf(zv[3]);
  float cn = fg * c_prev[idx] + ig * gg;
  float hn = og * tanhf(cn);
  h_out[idx] = hn;
  c_out[idx] = cn;
}

__global__ __launch_bounds__(256) void fb_proj_kernel(
    const float* __restrict__ h2n, const float* __restrict__ rnn_in,
    const float* __restrict__ Wp, const float* __restrict__ bp,
    float* __restrict__ mel, float* __restrict__ stops) {
  int b = blockIdx.x;
  int tid = threadIdx.x;
  __shared__ float row[1536];
  for (int i = tid; i < 1536; i += 256)
    row[i] = (i < 1024) ? h2n[(size_t)b * 1024 + i]
                        : rnn_in[(size_t)b * 768 + 256 + (i - 1024)];
  __syncthreads();
  if (tid < 81) {
    float s = bp[tid];
    for (int m = 0; m < 1536; ++m) s = fmaf(row[m], Wp[m * 81 + tid], s);
    if (tid < 80) mel[b * 80 + tid] = s;
    else stops[b] = s;
  }
}

// ---------------------------------------------------------------------------
extern "C" void kernel_launch(void* const* d_in, const int* in_sizes, int n_in,
                              void* d_out, int out_size, void* d_ws,
                              size_t ws_size, hipStream_t stream) {
  float* out = (float*)d_out;
  float* ws = (float*)d_ws;

  MegaArgs a;
  a.enc  = (const float*)d_in[0];
  a.mels = (const float*)d_in[1];
  a.prev = (const float*)d_in[2];
  a.h1   = (const float*)d_in[3];
  a.c1   = (const float*)d_in[4];
  a.h2   = (const float*)d_in[5];
  a.c2   = (const float*)d_in[6];
  a.Wp1  = (const float*)d_in[7];
  a.bp1  = (const float*)d_in[8];
  a.Wp2  = (const float*)d_in[9];
  a.bp2  = (const float*)d_in[10];
  a.Wq   = (const float*)d_in[11];
  a.Wk   = (const float*)d_in[12];
  a.bk   = (const float*)d_in[13];
  a.va   = (const float*)d_in[14];
  a.bsc  = (const float*)d_in[15];
  a.Wx1  = (const float*)d_in[16];
  a.Wh1  = (const float*)d_in[17];
  a.bl1  = (const float*)d_in[18];
  a.Wx2  = (const float*)d_in[19];
  a.Wh2  = (const float*)d_in[20];
  a.bl2  = (const float*)d_in[21];
  a.Wpj  = (const float*)d_in[22];
  a.bpj  = (const float*)d_in[23];

  a.mel    = out;            // 128*80
  a.stops  = out + 10240;    // 128
  a.aligno = out + 10368;    // 128*512
  a.h1n    = out + 75904;    // 128*1024
  a.c1n    = out + 206976;
  a.h2n    = out + 338048;
  a.c2n    = out + 469120;

  a.q_ws   = ws;             // 16384 f
  a.sc_ws  = ws + 16384;     // 65536 f
  a.rnn_in = ws + 81920;     // 98304 f
  a.parts  = ws + 180224;    // 8 * 524288 f
  a.WkT    = (__bf16*)a.parts;  // aliases parts head; dead before phase E

  void* args[] = {(void*)&a};
  hipError_t err = hipLaunchCooperativeKernel(
      (const void*)mega_kernel, dim3(256), dim3(512), args, 0, stream);
  if (err == hipSuccess) return;

  // ---------------- fallback: proven multi-kernel path ----------------
  hipLaunchKernelGGL(fb_prenet_kernel, dim3(192), dim3(256), 0, stream,
                     a.mels, a.Wp1, a.bp1, a.Wp2, a.bp2, a.Wq, a.Wk, a.WkT,
                     a.rnn_in, a.q_ws);
  hipLaunchKernelGGL(fb_score_kernel, dim3(4, 128), dim3(256), 0, stream,
                     a.enc, a.WkT, a.bk, a.q_ws, a.va, a.bsc, a.sc_ws);
  hipLaunchKernelGGL(fb_scan_kernel, dim3(128), dim3(512), 0, stream,
                     a.sc_ws, a.prev, a.aligno);
  hipLaunchKernelGGL(fb_att_part_kernel, dim3(8, 2, 128), dim3(256), 0, stream,
                     a.aligno, a.enc, a.rnn_in);
  hipLaunchKernelGGL(fb_zgemm_kernel, dim3(64, 4), dim3(256), 0, stream,
                     a.rnn_in, 768, a.Wx1, a.h1, 1024, a.Wh1, a.parts);
  hipLaunchKernelGGL(fb_gate_kernel, dim3(512), dim3(256), 0, stream,
                     a.parts, a.bl1, a.c1, a.h1n, a.c1n);
  hipLaunchKernelGGL(fb_zgemm_kernel, dim3(64, 4), dim3(256), 0, stream,
                     a.h1n, 1024, a.Wx2, a.h2, 1024, a.Wh2, a.parts);
  hipLaunchKernelGGL(fb_gate_kernel, dim3(512), dim3(256), 0, stream,
                     a.parts, a.bl2, a.c2, a.h2n, a.c2n);
  hipLaunchKernelGGL(fb_proj_kernel, dim3(128), dim3(256), 0, stream,
                     a.h2n, a.rnn_in, a.Wpj, a.bpj, a.mel, a.stops);
}

// Round 7
// 157.356 us; speedup vs baseline: 2.5392x; 2.5392x over previous
//
#include <hip/hip_runtime.h>
#include <math.h>

typedef float f32x4 __attribute__((ext_vector_type(4)));
typedef __bf16 bf16x8 __attribute__((ext_vector_type(8)));
typedef __bf16 bf16x4 __attribute__((ext_vector_type(4)));

// ---------------------------------------------------------------------------
// JAX threefry2x32 (exact port) + dropout mask replication.
// ---------------------------------------------------------------------------
#define PARTITIONABLE 1

__device__ __forceinline__ void threefry2x32(unsigned k0, unsigned k1,
                                             unsigned c0, unsigned c1,
                                             unsigned &o0, unsigned &o1) {
  unsigned ks2 = k0 ^ k1 ^ 0x1BD11BDAu;
  unsigned x0 = c0 + k0, x1 = c1 + k1;
#define ROTL(v, n) (((v) << (n)) | ((v) >> (32 - (n))))
#define R4(a, b, c, d)                                   \
  { x0 += x1; x1 = ROTL(x1, a); x1 ^= x0;                \
    x0 += x1; x1 = ROTL(x1, b); x1 ^= x0;                \
    x0 += x1; x1 = ROTL(x1, c); x1 ^= x0;                \
    x0 += x1; x1 = ROTL(x1, d); x1 ^= x0; }
  R4(13, 15, 26, 6);  x0 += k1;  x1 += ks2 + 1u;
  R4(17, 29, 16, 24); x0 += ks2; x1 += k0 + 2u;
  R4(13, 15, 26, 6);  x0 += k0;  x1 += k1 + 3u;
  R4(17, 29, 16, 24); x0 += k1;  x1 += ks2 + 4u;
  R4(13, 15, 26, 6);  x0 += ks2; x1 += k0 + 5u;
  o0 = x0; o1 = x1;
#undef R4
#undef ROTL
}

__device__ __forceinline__ float dropout_scale(int layer, unsigned i) {
#if PARTITIONABLE
  unsigned d0, d1, y0, y1;
  threefry2x32(0u, 7u, 0u, (unsigned)layer, d0, d1);
  threefry2x32(d0, d1, 0u, i, y0, y1);
  unsigned bits = y0 ^ y1;
#else
  unsigned a0, b0, a1, b1v, y0, y1;
  threefry2x32(0u, 7u, 0u, 2u, a0, b0);
  threefry2x32(0u, 7u, 1u, 3u, a1, b1v);
  unsigned k0 = (layer == 0) ? a0 : b0;
  unsigned k1 = (layer == 0) ? a1 : b1v;
  const unsigned half = 16384u;
  unsigned lane = (i < half) ? 0u : 1u;
  unsigned j = lane ? (i - half) : i;
  threefry2x32(k0, k1, j, j + half, y0, y1);
  unsigned bits = lane ? y1 : y0;
#endif
  return (bits & 0x80000000u) ? 0.0f : 2.0f;
}

__device__ __forceinline__ float sigmoidf(float x) {
  return 1.0f / (1.0f + expf(-x));
}

// ---------------------------------------------------------------------------
// 1) Prenet (blocks 0..127) + WkT transpose prep (blocks 128..191).
// ---------------------------------------------------------------------------
__global__ __launch_bounds__(256) void prenet_kernel(
    const float* __restrict__ mels, const float* __restrict__ W1,
    const float* __restrict__ b1, const float* __restrict__ W2,
    const float* __restrict__ b2, const float* __restrict__ Wq,
    const float* __restrict__ Wk, __bf16* __restrict__ WkT,
    float* __restrict__ rnn_in, float* __restrict__ q_out) {
  int blk = blockIdx.x;
  int j = threadIdx.x;
  if (blk >= 128) {  // WkT prep: Wk [512][128] f32 -> WkT [128][512] bf16
    int gid = (blk - 128) * 256 + j;
    int a = gid & 127;
    int k4 = (gid >> 7) * 4;
    bf16x4 w;
    for (int i = 0; i < 4; ++i) w[i] = (__bf16)Wk[(size_t)(k4 + i) * 128 + a];
    *reinterpret_cast<bf16x4*>(&WkT[(size_t)a * 512 + k4]) = w;
    return;
  }
  int b = blk;
  __shared__ float mel_s[80];
  __shared__ float x1_s[256];
  __shared__ float x2_s[256];
  if (j < 80) mel_s[j] = mels[b * 80 + j];
  __syncthreads();
  float s = b1[j];
  for (int m = 0; m < 80; ++m) s = fmaf(mel_s[m], W1[m * 256 + j], s);
  s = fmaxf(s, 0.0f) * dropout_scale(0, (unsigned)(b * 256 + j));
  x1_s[j] = s;
  __syncthreads();
  float s2 = b2[j];
  for (int m = 0; m < 256; ++m) s2 = fmaf(x1_s[m], W2[m * 256 + j], s2);
  s2 = fmaxf(s2, 0.0f) * dropout_scale(1, (unsigned)(b * 256 + j));
  x2_s[j] = s2;
  rnn_in[(size_t)b * 768 + j] = s2;
  __syncthreads();
  if (j < 128) {
    float sq = 0.0f;
    for (int m = 0; m < 256; ++m) sq = fmaf(x2_s[m], Wq[m * 128 + j], sq);
    q_out[b * 128 + j] = sq;
  }
}

// ---------------------------------------------------------------------------
// 2) score via MFMA (R3-proven structure). t_base offsets the tile; if
//    flag != nullptr and flag[b] set, write zero scores and skip all work
//    (cp_excl underflowed to 0 for this b => alignments are 0 regardless).
// ---------------------------------------------------------------------------
__global__ __launch_bounds__(256) void score_mfma_kernel(
    const float* __restrict__ enc, const __bf16* __restrict__ WkT,
    const float* __restrict__ bk, const float* __restrict__ q,
    const float* __restrict__ va_g, const float* __restrict__ bscore,
    float* __restrict__ score, int t_base, const int* __restrict__ flag) {
  int b = blockIdx.y;
  int t0 = t_base + blockIdx.x * 128;
  int tid = threadIdx.x;
  if (flag && flag[b]) {
    if (tid < 128) score[b * 512 + t0 + tid] = 0.0f;
    return;
  }
  int lane = tid & 63, wid = tid >> 6;
  int wr = wid >> 1, wc = wid & 1;
  __shared__ __align__(16) __bf16 Eb[128 * 64];
  __shared__ __align__(16) __bf16 Wb[128 * 64];
  __shared__ float red[128][4];

  f32x4 acc[4][4];
#pragma unroll
  for (int i = 0; i < 4; ++i)
#pragma unroll
    for (int j = 0; j < 4; ++j) acc[i][j] = (f32x4){0.f, 0.f, 0.f, 0.f};

  float qv[4], vav[4];
#pragma unroll
  for (int j = 0; j < 4; ++j) {
    int a = wc * 64 + j * 16 + (lane & 15);
    qv[j] = q[b * 128 + a] + bk[a];
    vav[j] = va_g[a];
  }
  int er = tid >> 4, ek4 = (tid & 15) * 4;
  int wrw = tid >> 3, wkc = (tid & 7) * 8;

  for (int k0 = 0; k0 < 512; k0 += 64) {
    __syncthreads();
#pragma unroll
    for (int p = 0; p < 8; ++p) {
      int t = er + p * 16;
      const float4 v = *reinterpret_cast<const float4*>(
          &enc[((size_t)(b * 512 + t0 + t)) * 512 + k0 + ek4]);
      bf16x4 w;
      w[0] = (__bf16)v.x; w[1] = (__bf16)v.y;
      w[2] = (__bf16)v.z; w[3] = (__bf16)v.w;
      *reinterpret_cast<bf16x4*>(&Eb[t * 64 + (ek4 ^ ((t & 7) << 3))]) = w;
    }
#pragma unroll
    for (int p = 0; p < 4; ++p) {
      int a = wrw + p * 32;
      uint4 v = *reinterpret_cast<const uint4*>(&WkT[(size_t)a * 512 + k0 + wkc]);
      *reinterpret_cast<uint4*>(&Wb[a * 64 + (wkc ^ ((a & 7) << 3))]) = v;
    }
    __syncthreads();
#pragma unroll
    for (int kk = 0; kk < 64; kk += 32) {
      bf16x8 af[4], bfr[4];
      int kl = kk + (lane >> 4) * 8;
#pragma unroll
      for (int i = 0; i < 4; ++i) {
        int t = wr * 64 + i * 16 + (lane & 15);
        af[i] = *reinterpret_cast<const bf16x8*>(&Eb[t * 64 + (kl ^ ((t & 7) << 3))]);
      }
#pragma unroll
      for (int j = 0; j < 4; ++j) {
        int a = wc * 64 + j * 16 + (lane & 15);
        bfr[j] = *reinterpret_cast<const bf16x8*>(&Wb[a * 64 + (kl ^ ((a & 7) << 3))]);
      }
#pragma unroll
      for (int i = 0; i < 4; ++i)
#pragma unroll
        for (int j = 0; j < 4; ++j)
          acc[i][j] = __builtin_amdgcn_mfma_f32_16x16x32_bf16(
              af[i], bfr[j], acc[i][j], 0, 0, 0);
    }
  }

#pragma unroll
  for (int i = 0; i < 4; ++i) {
#pragma unroll
    for (int r = 0; r < 4; ++r) {
      float s = 0.0f;
#pragma unroll
      for (int j = 0; j < 4; ++j) s += tanhf(qv[j] + acc[i][j][r]) * vav[j];
      s += __shfl_xor(s, 1, 64);
      s += __shfl_xor(s, 2, 64);
      s += __shfl_xor(s, 4, 64);
      s += __shfl_xor(s, 8, 64);
      if ((lane & 15) == 0)
        red[wr * 64 + i * 16 + (lane >> 4) * 4 + r][wc] = s;
    }
  }
  __syncthreads();
  if (tid < 128)
    score[b * 512 + t0 + tid] = red[tid][0] + red[tid][1] + bscore[0];
}

// ---------------------------------------------------------------------------
// 2b) cp-underflow flag: flag[b] = ( prod_{t<256} (1 - sigmoid(score)) tiny ).
// ---------------------------------------------------------------------------
__global__ __launch_bounds__(256) void cpflag_kernel(
    const float* __restrict__ score, int* __restrict__ flag) {
  int b = blockIdx.x, t = threadIdx.x;
  __shared__ float s[256];
  float p = sigmoidf(score[b * 512 + t]);
  s[t] = 1.0f - p;
  __syncthreads();
  for (int off = 128; off >= 1; off >>= 1) {
    if (t < off) s[t] *= s[t + off];
    __syncthreads();
  }
  if (t == 0) flag[b] = (s[0] < 1e-30f && s[0] > -1e-30f) ? 1 : 0;
}

// ---------------------------------------------------------------------------
// 3) Monotonic-attention scan (R3)
// ---------------------------------------------------------------------------
__global__ __launch_bounds__(512) void scan_kernel(
    const float* __restrict__ score, const float* __restrict__ prev_align,
    float* __restrict__ align_out) {
  int b = blockIdx.x, t = threadIdx.x;
  __shared__ float s[512];
  float p = sigmoidf(score[b * 512 + t]);
  float omp = 1.0f - p;
  s[t] = omp;
  __syncthreads();
  for (int off = 1; off < 512; off <<= 1) {
    float v = (t >= off) ? s[t - off] : 1.0f;
    __syncthreads();
    if (t >= off) s[t] *= v;
    __syncthreads();
  }
  float cp_excl = (t == 0) ? 1.0f : s[t - 1];
  __syncthreads();
  float denom = fminf(fmaxf(cp_excl, 1e-10f), 1.0f);
  float r = prev_align[b * 512 + t] / denom;
  s[t] = r;
  __syncthreads();
  for (int off = 1; off < 512; off <<= 1) {
    float v = (t >= off) ? s[t - off] : 0.0f;
    __syncthreads();
    if (t >= off) s[t] += v;
    __syncthreads();
  }
  align_out[b * 512 + t] = p * cp_excl * s[t];
}

// ---------------------------------------------------------------------------
// 4) attentions (R3: partials + combine)
// ---------------------------------------------------------------------------
__global__ __launch_bounds__(256) void att_part_kernel(
    const float* __restrict__ align, const float* __restrict__ enc,
    float* __restrict__ ap) {
  int tc = blockIdx.x;
  int vt = blockIdx.y;
  int b = blockIdx.z;
  int tid = threadIdx.x;
  int v = vt * 256 + tid;
  __shared__ float al[64];
  if (tid < 64) al[tid] = align[b * 512 + tc * 64 + tid];
  __syncthreads();
  float acc = 0.0f;
  for (int tt = 0; tt < 64; ++tt) {
    float a = al[tt];
    if (a != 0.0f)
      acc = fmaf(a, enc[((size_t)(b * 512 + tc * 64 + tt)) * 512 + v], acc);
  }
  ap[((size_t)tc * 128 + b) * 512 + v] = acc;
}

__global__ __launch_bounds__(256) void att_comb_kernel(
    const float* __restrict__ ap, float* __restrict__ rnn_in,
    float* __restrict__ proj_in) {
  int b = blockIdx.x;
  int v = blockIdx.y * 256 + threadIdx.x;
  float s = 0.0f;
  for (int tc = 0; tc < 8; ++tc) s += ap[((size_t)tc * 128 + b) * 512 + v];
  rnn_in[(size_t)b * 768 + 256 + v] = s;
  proj_in[(size_t)b * 1536 + 1024 + v] = s;
}

// ---------------------------------------------------------------------------
// 5) LSTM z partials via MFMA (R3: 128-col blocks, grid (32,8))
// ---------------------------------------------------------------------------
__global__ __launch_bounds__(256) void zgemm_mfma_kernel(
    const float* __restrict__ A0, int K0, const float* __restrict__ W0,
    const float* __restrict__ A1, int K1, const float* __restrict__ W1,
    float* __restrict__ parts) {
  int cb = blockIdx.x;   // 0..31
  int zp = blockIdx.y;   // 0..7
  int seg = zp >> 2, kq = zp & 3;
  const float* A = seg ? A1 : A0;
  const float* W = seg ? W1 : W0;
  int K = seg ? K1 : K0;
  int kc = K >> 2;                 // 192 or 256
  int kbeg = kq * kc, kend = kbeg + kc;
  int tid = threadIdx.x;
  int lane = tid & 63, wid = tid >> 6;
  int wr = wid >> 1, wc = wid & 1;
  __shared__ __align__(16) __bf16 Ab[128 * 64];

  f32x4 acc[4][4];
#pragma unroll
  for (int i = 0; i < 4; ++i)
#pragma unroll
    for (int j = 0; j < 4; ++j) acc[i][j] = (f32x4){0.f, 0.f, 0.f, 0.f};

  int n_base = cb * 128 + wc * 64 + (lane & 15);
  int koct = (lane >> 4) * 8;

  for (int k0 = kbeg; k0 < kend; k0 += 64) {
    __syncthreads();
    {
      int r = tid >> 4;
      int k4 = (tid & 15) * 4;
#pragma unroll
      for (int p = 0; p < 8; ++p) {
        int row = r + p * 16;
        const float4 v = *reinterpret_cast<const float4*>(
            &A[(size_t)row * K + k0 + k4]);
        bf16x4 w;
        w[0] = (__bf16)v.x; w[1] = (__bf16)v.y;
        w[2] = (__bf16)v.z; w[3] = (__bf16)v.w;
        *reinterpret_cast<bf16x4*>(&Ab[row * 64 + (k4 ^ ((row & 7) << 3))]) = w;
      }
    }
    __syncthreads();
#pragma unroll
    for (int kk = 0; kk < 64; kk += 32) {
      bf16x8 af[4];
      int kl = kk + koct;
#pragma unroll
      for (int i = 0; i < 4; ++i) {
        int t = wr * 64 + i * 16 + (lane & 15);
        af[i] = *reinterpret_cast<const bf16x8*>(&Ab[t * 64 + (kl ^ ((t & 7) << 3))]);
      }
      bf16x8 bfr[4];
      const float* wp = W + (size_t)(k0 + kk + koct) * 4096 + n_base;
#pragma unroll
      for (int jf = 0; jf < 4; ++jf) {
        const float* wq = wp + jf * 16;
        bf16x8 bv;
#pragma unroll
        for (int j = 0; j < 8; ++j) bv[j] = (__bf16)wq[(size_t)j * 4096];
        bfr[jf] = bv;
      }
#pragma unroll
      for (int i = 0; i < 4; ++i)
#pragma unroll
        for (int jf = 0; jf < 4; ++jf)
          acc[i][jf] = __builtin_amdgcn_mfma_f32_16x16x32_bf16(
              af[i], bfr[jf], acc[i][jf], 0, 0, 0);
    }
  }

  float* outp = parts + (size_t)zp * (128 * 4096);
#pragma unroll
  for (int i = 0; i < 4; ++i) {
#pragma unroll
    for (int jf = 0; jf < 4; ++jf) {
#pragma unroll
      for (int r = 0; r < 4; ++r) {
        int row = wr * 64 + i * 16 + ((lane >> 4) << 2) + r;
        int col = cb * 128 + wc * 64 + jf * 16 + (lane & 15);
        outp[(size_t)row * 4096 + col] = acc[i][jf][r];
      }
    }
  }
}

// ---------------------------------------------------------------------------
// 6) LSTM gates: z = sum of 8 parts + bias (R3, with h copy to dst2)
// ---------------------------------------------------------------------------
__global__ __launch_bounds__(256) void gate_kernel(
    const float* __restrict__ parts, const float* __restrict__ bias,
    const float* __restrict__ c_prev, float* __restrict__ h_out,
    float* __restrict__ c_out, float* __restrict__ h_dst2, int ld2) {
  int idx = blockIdx.x * 256 + threadIdx.x;
  int b = idx >> 10, j = idx & 1023;
  float zv[4];
  for (int g = 0; g < 4; ++g) {
    size_t off = (size_t)b * 4096 + g * 1024 + j;
    float s = bias[g * 1024 + j];
    for (int p = 0; p < 8; ++p) s += parts[(size_t)p * (128 * 4096) + off];
    zv[g] = s;
  }
  float ig = sigmoidf(zv[0]);
  float fg = sigmoidf(zv[1]);
  float gg = tanhf(zv[2]);
  float og = sigmoidf(zv[3]);
  float cn = fg * c_prev[idx] + ig * gg;
  float hn = og * tanhf(cn);
  h_out[idx] = hn;
  c_out[idx] = cn;
  if (h_dst2) h_dst2[(size_t)b * ld2 + j] = hn;
}

// ---------------------------------------------------------------------------
// 7) Projection (R3)
// ---------------------------------------------------------------------------
__global__ __launch_bounds__(256) void proj_kernel(
    const float* __restrict__ proj_in, const float* __restrict__ Wp,
    const float* __restrict__ bp, float* __restrict__ mel,
    float* __restrict__ stops) {
  int b = blockIdx.x;
  int tid = threadIdx.x;
  __shared__ float row[1536];
  for (int i = tid; i < 1536; i += 256) row[i] = proj_in[(size_t)b * 1536 + i];
  __syncthreads();
  if (tid < 81) {
    float s = bp[tid];
    for (int m = 0; m < 1536; ++m) s = fmaf(row[m], Wp[m * 81 + tid], s);
    if (tid < 80) mel[b * 80 + tid] = s;
    else stops[b] = s;
  }
}

// ---------------------------------------------------------------------------
extern "C" void kernel_launch(void* const* d_in, const int* in_sizes, int n_in,
                              void* d_out, int out_size, void* d_ws,
                              size_t ws_size, hipStream_t stream) {
  const float* enc  = (const float*)d_in[0];
  const float* mels = (const float*)d_in[1];
  const float* prev = (const float*)d_in[2];
  const float* h1   = (const float*)d_in[3];
  const float* c1   = (const float*)d_in[4];
  const float* h2   = (const float*)d_in[5];
  const float* c2   = (const float*)d_in[6];
  const float* Wp1  = (const float*)d_in[7];
  const float* bp1  = (const float*)d_in[8];
  const float* Wp2  = (const float*)d_in[9];
  const float* bp2  = (const float*)d_in[10];
  const float* Wq   = (const float*)d_in[11];
  const float* Wk   = (const float*)d_in[12];
  const float* bk   = (const float*)d_in[13];
  const float* va   = (const float*)d_in[14];
  const float* bsc  = (const float*)d_in[15];
  const float* Wx1  = (const float*)d_in[16];
  const float* Wh1  = (const float*)d_in[17];
  const float* bl1  = (const float*)d_in[18];
  const float* Wx2  = (const float*)d_in[19];
  const float* Wh2  = (const float*)d_in[20];
  const float* bl2  = (const float*)d_in[21];
  const float* Wpj  = (const float*)d_in[22];
  const float* bpj  = (const float*)d_in[23];

  float* out = (float*)d_out;
  float* mel    = out;            // 128*80
  float* stops  = out + 10240;    // 128
  float* aligno = out + 10368;    // 128*512
  float* h1n    = out + 75904;    // 128*1024
  float* c1n    = out + 206976;
  float* h2n    = out + 338048;
  float* c2n    = out + 469120;

  float* ws = (float*)d_ws;
  float* q_ws   = ws;              // 16384
  float* sc_ws  = ws + 16384;      // 65536
  float* rnn_in = ws + 81920;      // 128*768
  float* prj_in = ws + 180224;     // 128*1536
  float* parts  = ws + 376832;     // 8 * 128*4096 = 4,194,304
  float* ap_ws  = ws + 4571136;    // 8*128*512 = 524,288
  int*   flag   = (int*)(ws + 5095424);  // 128 ints
  // WkT (bf16, 128KB) aliases head of `parts` — consumed before zgemm runs.
  __bf16* WkT = (__bf16*)parts;

  hipLaunchKernelGGL(prenet_kernel, dim3(192), dim3(256), 0, stream,
                     mels, Wp1, bp1, Wp2, bp2, Wq, Wk, WkT, rnn_in, q_ws);
  // score t < 256 (always full work)
  hipLaunchKernelGGL(score_mfma_kernel, dim3(2, 128), dim3(256), 0, stream,
                     enc, WkT, bk, q_ws, va, bsc, sc_ws, 0, (const int*)nullptr);
  // cp-underflow flags from first 256 scores
  hipLaunchKernelGGL(cpflag_kernel, dim3(128), dim3(256), 0, stream,
                     sc_ws, flag);
  // score t >= 256 (skips enc read for flagged b)
  hipLaunchKernelGGL(score_mfma_kernel, dim3(2, 128), dim3(256), 0, stream,
                     enc, WkT, bk, q_ws, va, bsc, sc_ws, 256, (const int*)flag);
  hipLaunchKernelGGL(scan_kernel, dim3(128), dim3(512), 0, stream,
                     sc_ws, prev, aligno);
  hipLaunchKernelGGL(att_part_kernel, dim3(8, 2, 128), dim3(256), 0, stream,
                     aligno, enc, ap_ws);
  hipLaunchKernelGGL(att_comb_kernel, dim3(128, 2), dim3(256), 0, stream,
                     ap_ws, rnn_in, prj_in);
  hipLaunchKernelGGL(zgemm_mfma_kernel, dim3(32, 8), dim3(256), 0, stream,
                     rnn_in, 768, Wx1, h1, 1024, Wh1, parts);
  hipLaunchKernelGGL(gate_kernel, dim3(512), dim3(256), 0, stream,
                     parts, bl1, c1, h1n, c1n, (float*)nullptr, 0);
  hipLaunchKernelGGL(zgemm_mfma_kernel, dim3(32, 8), dim3(256), 0, stream,
                     h1n, 1024, Wx2, h2, 1024, Wh2, parts);
  hipLaunchKernelGGL(gate_kernel, dim3(512), dim3(256), 0, stream,
                     parts, bl2, c2, h2n, c2n, prj_in, 1536);
  hipLaunchKernelGGL(proj_kernel, dim3(128), dim3(256), 0, stream,
                     prj_in, Wpj, bpj, mel, stops);
}

// Round 8
// 137.096 us; speedup vs baseline: 2.9145x; 1.1478x over previous
//
#include <hip/hip_runtime.h>
#include <math.h>

typedef float f32x4 __attribute__((ext_vector_type(4)));
typedef __bf16 bf16x8 __attribute__((ext_vector_type(8)));
typedef __bf16 bf16x4 __attribute__((ext_vector_type(4)));

// ---------------------------------------------------------------------------
// JAX threefry2x32 (exact port) + dropout mask replication.
// ---------------------------------------------------------------------------
#define PARTITIONABLE 1

__device__ __forceinline__ void threefry2x32(unsigned k0, unsigned k1,
                                             unsigned c0, unsigned c1,
                                             unsigned &o0, unsigned &o1) {
  unsigned ks2 = k0 ^ k1 ^ 0x1BD11BDAu;
  unsigned x0 = c0 + k0, x1 = c1 + k1;
#define ROTL(v, n) (((v) << (n)) | ((v) >> (32 - (n))))
#define R4(a, b, c, d)                                   \
  { x0 += x1; x1 = ROTL(x1, a); x1 ^= x0;                \
    x0 += x1; x1 = ROTL(x1, b); x1 ^= x0;                \
    x0 += x1; x1 = ROTL(x1, c); x1 ^= x0;                \
    x0 += x1; x1 = ROTL(x1, d); x1 ^= x0; }
  R4(13, 15, 26, 6);  x0 += k1;  x1 += ks2 + 1u;
  R4(17, 29, 16, 24); x0 += ks2; x1 += k0 + 2u;
  R4(13, 15, 26, 6);  x0 += k0;  x1 += k1 + 3u;
  R4(17, 29, 16, 24); x0 += k1;  x1 += ks2 + 4u;
  R4(13, 15, 26, 6);  x0 += ks2; x1 += k0 + 5u;
  o0 = x0; o1 = x1;
#undef R4
#undef ROTL
}

__device__ __forceinline__ float dropout_scale(int layer, unsigned i) {
#if PARTITIONABLE
  unsigned d0, d1, y0, y1;
  threefry2x32(0u, 7u, 0u, (unsigned)layer, d0, d1);
  threefry2x32(d0, d1, 0u, i, y0, y1);
  unsigned bits = y0 ^ y1;
#else
  unsigned a0, b0, a1, b1v, y0, y1;
  threefry2x32(0u, 7u, 0u, 2u, a0, b0);
  threefry2x32(0u, 7u, 1u, 3u, a1, b1v);
  unsigned k0 = (layer == 0) ? a0 : b0;
  unsigned k1 = (layer == 0) ? a1 : b1v;
  const unsigned half = 16384u;
  unsigned lane = (i < half) ? 0u : 1u;
  unsigned j = lane ? (i - half) : i;
  threefry2x32(k0, k1, j, j + half, y0, y1);
  unsigned bits = lane ? y1 : y0;
#endif
  return (bits & 0x80000000u) ? 0.0f : 2.0f;
}

__device__ __forceinline__ float sigmoidf(float x) {
  return 1.0f / (1.0f + expf(-x));
}

// ---------------------------------------------------------------------------
// 1) Prenet (blocks 0..127) + WkT transpose prep (blocks 128..191).
//    Prenet zeroes rnn_in[:,256:768] so att_part can atomicAdd into it.
// ---------------------------------------------------------------------------
__global__ __launch_bounds__(256) void prenet_kernel(
    const float* __restrict__ mels, const float* __restrict__ W1,
    const float* __restrict__ b1, const float* __restrict__ W2,
    const float* __restrict__ b2, const float* __restrict__ Wq,
    const float* __restrict__ Wk, __bf16* __restrict__ WkT,
    float* __restrict__ rnn_in, float* __restrict__ q_out) {
  int blk = blockIdx.x;
  int j = threadIdx.x;
  if (blk >= 128) {  // WkT prep: Wk [512][128] f32 -> WkT [128][512] bf16
    int gid = (blk - 128) * 256 + j;
    int a = gid & 127;
    int k4 = (gid >> 7) * 4;
    bf16x4 w;
    for (int i = 0; i < 4; ++i) w[i] = (__bf16)Wk[(size_t)(k4 + i) * 128 + a];
    *reinterpret_cast<bf16x4*>(&WkT[(size_t)a * 512 + k4]) = w;
    return;
  }
  int b = blk;
  __shared__ float mel_s[80];
  __shared__ float x1_s[256];
  __shared__ float x2_s[256];
  if (j < 80) mel_s[j] = mels[b * 80 + j];
  // zero attention slice (att_part accumulates there)
  rnn_in[(size_t)b * 768 + 256 + j] = 0.0f;
  rnn_in[(size_t)b * 768 + 512 + j] = 0.0f;
  __syncthreads();
  float s = b1[j];
  for (int m = 0; m < 80; ++m) s = fmaf(mel_s[m], W1[m * 256 + j], s);
  s = fmaxf(s, 0.0f) * dropout_scale(0, (unsigned)(b * 256 + j));
  x1_s[j] = s;
  __syncthreads();
  float s2 = b2[j];
  for (int m = 0; m < 256; ++m) s2 = fmaf(x1_s[m], W2[m * 256 + j], s2);
  s2 = fmaxf(s2, 0.0f) * dropout_scale(1, (unsigned)(b * 256 + j));
  x2_s[j] = s2;
  rnn_in[(size_t)b * 768 + j] = s2;
  __syncthreads();
  if (j < 128) {
    float sq = 0.0f;
    for (int m = 0; m < 256; ++m) sq = fmaf(x2_s[m], Wq[m * 128 + j], sq);
    q_out[b * 128 + j] = sq;
  }
}

// ---------------------------------------------------------------------------
// 2) score via MFMA, 64-t tiles (512 blocks per half -> 2 blocks/CU).
//    If flag[b] set: pure return (scan handles the t>=256 region exactly).
// ---------------------------------------------------------------------------
__global__ __launch_bounds__(256) void score64_kernel(
    const float* __restrict__ enc, const __bf16* __restrict__ WkT,
    const float* __restrict__ bk, const float* __restrict__ q,
    const float* __restrict__ va_g, const float* __restrict__ bscore,
    float* __restrict__ score, int t_base, const int* __restrict__ flag) {
  int b = blockIdx.y;
  if (flag && flag[b]) return;
  int t0 = t_base + blockIdx.x * 64;
  int tid = threadIdx.x;
  int lane = tid & 63, wid = tid >> 6;
  int wr = wid >> 1, wc = wid & 1;  // 2x2 waves: 32t x 64a each
  __shared__ __align__(16) __bf16 Eb[64 * 64];
  __shared__ __align__(16) __bf16 Wb[128 * 64];
  __shared__ float red[64][2];

  f32x4 acc[2][4];
#pragma unroll
  for (int i = 0; i < 2; ++i)
#pragma unroll
    for (int j = 0; j < 4; ++j) acc[i][j] = (f32x4){0.f, 0.f, 0.f, 0.f};

  float qv[4], vav[4];
#pragma unroll
  for (int j = 0; j < 4; ++j) {
    int a = wc * 64 + j * 16 + (lane & 15);
    qv[j] = q[b * 128 + a] + bk[a];
    vav[j] = va_g[a];
  }
  int er = tid >> 4, ek4 = (tid & 15) * 4;
  int wrw = tid >> 3, wkc = (tid & 7) * 8;

  for (int k0 = 0; k0 < 512; k0 += 64) {
    __syncthreads();
#pragma unroll
    for (int p = 0; p < 4; ++p) {  // enc: 64 rows x 64 k
      int t = er + p * 16;
      const float4 v = *reinterpret_cast<const float4*>(
          &enc[((size_t)(b * 512 + t0 + t)) * 512 + k0 + ek4]);
      bf16x4 w;
      w[0] = (__bf16)v.x; w[1] = (__bf16)v.y;
      w[2] = (__bf16)v.z; w[3] = (__bf16)v.w;
      *reinterpret_cast<bf16x4*>(&Eb[t * 64 + (ek4 ^ ((t & 7) << 3))]) = w;
    }
#pragma unroll
    for (int p = 0; p < 4; ++p) {  // WkT: 128 a x 64 k
      int a = wrw + p * 32;
      uint4 v = *reinterpret_cast<const uint4*>(&WkT[(size_t)a * 512 + k0 + wkc]);
      *reinterpret_cast<uint4*>(&Wb[a * 64 + (wkc ^ ((a & 7) << 3))]) = v;
    }
    __syncthreads();
#pragma unroll
    for (int kk = 0; kk < 64; kk += 32) {
      int kl = kk + (lane >> 4) * 8;
      bf16x8 af[2], bfr[4];
#pragma unroll
      for (int i = 0; i < 2; ++i) {
        int t = wr * 32 + i * 16 + (lane & 15);
        af[i] = *reinterpret_cast<const bf16x8*>(&Eb[t * 64 + (kl ^ ((t & 7) << 3))]);
      }
#pragma unroll
      for (int j = 0; j < 4; ++j) {
        int a = wc * 64 + j * 16 + (lane & 15);
        bfr[j] = *reinterpret_cast<const bf16x8*>(&Wb[a * 64 + (kl ^ ((a & 7) << 3))]);
      }
#pragma unroll
      for (int i = 0; i < 2; ++i)
#pragma unroll
        for (int j = 0; j < 4; ++j)
          acc[i][j] = __builtin_amdgcn_mfma_f32_16x16x32_bf16(
              af[i], bfr[j], acc[i][j], 0, 0, 0);
    }
  }

#pragma unroll
  for (int i = 0; i < 2; ++i) {
#pragma unroll
    for (int r = 0; r < 4; ++r) {
      float s = 0.0f;
#pragma unroll
      for (int j = 0; j < 4; ++j) s += tanhf(qv[j] + acc[i][j][r]) * vav[j];
      s += __shfl_xor(s, 1, 64);
      s += __shfl_xor(s, 2, 64);
      s += __shfl_xor(s, 4, 64);
      s += __shfl_xor(s, 8, 64);
      if ((lane & 15) == 0)
        red[wr * 32 + i * 16 + (lane >> 4) * 4 + r][wc] = s;
    }
  }
  __syncthreads();
  if (tid < 64)
    score[b * 512 + t0 + tid] = red[tid][0] + red[tid][1] + bscore[0];
}

// ---------------------------------------------------------------------------
// 2b) cp-underflow flag: prod_{t<256}(1 - sigmoid(score)) underflowed to 0.
// ---------------------------------------------------------------------------
__global__ __launch_bounds__(256) void cpflag_kernel(
    const float* __restrict__ score, int* __restrict__ flag) {
  int b = blockIdx.x, t = threadIdx.x;
  __shared__ float s[256];
  float p = sigmoidf(score[b * 512 + t]);
  s[t] = 1.0f - p;
  __syncthreads();
  for (int off = 128; off >= 1; off >>= 1) {
    if (t < off) s[t] *= s[t + off];
    __syncthreads();
  }
  if (t == 0) flag[b] = (s[0] < 1e-30f && s[0] > -1e-30f) ? 1 : 0;
}

// ---------------------------------------------------------------------------
// 3) Monotonic-attention scan. For flagged b, scores for t>=256 were never
//    computed: use p=0 there (exact — cp_excl is exactly 0 for t>=256, so
//    align = p*cp*cumsum = 0 regardless of p).
// ---------------------------------------------------------------------------
__global__ __launch_bounds__(512) void scan_kernel(
    const float* __restrict__ score, const float* __restrict__ prev_align,
    const int* __restrict__ flag, float* __restrict__ align_out) {
  int b = blockIdx.x, t = threadIdx.x;
  int flg = flag[b];
  __shared__ float s[512];
  float sc = (t < 256 || !flg) ? score[b * 512 + t] : -1e30f;
  float p = sigmoidf(sc);
  float omp = 1.0f - p;
  s[t] = omp;
  __syncthreads();
  for (int off = 1; off < 512; off <<= 1) {
    float v = (t >= off) ? s[t - off] : 1.0f;
    __syncthreads();
    if (t >= off) s[t] *= v;
    __syncthreads();
  }
  float cp_excl = (t == 0) ? 1.0f : s[t - 1];
  __syncthreads();
  float denom = fminf(fmaxf(cp_excl, 1e-10f), 1.0f);
  float r = prev_align[b * 512 + t] / denom;
  s[t] = r;
  __syncthreads();
  for (int off = 1; off < 512; off <<= 1) {
    float v = (t >= off) ? s[t - off] : 0.0f;
    __syncthreads();
    if (t >= off) s[t] += v;
    __syncthreads();
  }
  align_out[b * 512 + t] = p * cp_excl * s[t];
}

// ---------------------------------------------------------------------------
// 4) attention context: chunk-skip + atomicAdd into rnn_in[:,256:768].
// ---------------------------------------------------------------------------
__global__ __launch_bounds__(256) void att_part_kernel(
    const float* __restrict__ align, const float* __restrict__ enc,
    float* __restrict__ rnn_in) {
  int tc = blockIdx.x;
  int vt = blockIdx.y;
  int b = blockIdx.z;
  int tid = threadIdx.x;
  int v = vt * 256 + tid;
  __shared__ float al[64];
  __shared__ int flag;
  if (tid == 0) flag = 0;
  __syncthreads();
  if (tid < 64) {
    float a = align[b * 512 + tc * 64 + tid];
    al[tid] = a;
    if (a != 0.0f) flag = 1;
  }
  __syncthreads();
  if (!flag) return;
  float acc = 0.0f;
  for (int tt = 0; tt < 64; ++tt) {
    float a = al[tt];
    if (a != 0.0f)
      acc = fmaf(a, enc[((size_t)(b * 512 + tc * 64 + tt)) * 512 + v], acc);
  }
  atomicAdd(&rnn_in[(size_t)b * 768 + 256 + v], acc);
}

// ---------------------------------------------------------------------------
// 5) LSTM z partials via MFMA: grid (64,8) = 512 blocks (2/CU).
//    Block = 128 rows x 64 cols, K-quarter. zp: seg=zp>>2, kq=zp&3.
// ---------------------------------------------------------------------------
__global__ __launch_bounds__(256) void zgemm_mfma_kernel(
    const float* __restrict__ A0, int K0, const float* __restrict__ W0,
    const float* __restrict__ A1, int K1, const float* __restrict__ W1,
    float* __restrict__ parts) {
  int cb = blockIdx.x;   // 0..63
  int zp = blockIdx.y;   // 0..7
  int seg = zp >> 2, kq = zp & 3;
  const float* A = seg ? A1 : A0;
  const float* W = seg ? W1 : W0;
  int K = seg ? K1 : K0;
  int kc = K >> 2;                 // 192 or 256
  int kbeg = kq * kc, kend = kbeg + kc;
  int tid = threadIdx.x;
  int lane = tid & 63, wid = tid >> 6;
  int wr = wid >> 1, wc = wid & 1;  // 2x2 waves: 64 rows x 32 cols each
  __shared__ __align__(16) __bf16 Ab[128 * 64];

  f32x4 acc[4][2];
#pragma unroll
  for (int i = 0; i < 4; ++i)
#pragma unroll
    for (int j = 0; j < 2; ++j) acc[i][j] = (f32x4){0.f, 0.f, 0.f, 0.f};

  int n_base = cb * 64 + wc * 32 + (lane & 15);
  int koct = (lane >> 4) * 8;

  for (int k0 = kbeg; k0 < kend; k0 += 64) {
    __syncthreads();
    {
      int r = tid >> 4;
      int k4 = (tid & 15) * 4;
#pragma unroll
      for (int p = 0; p < 8; ++p) {
        int row = r + p * 16;
        const float4 v = *reinterpret_cast<const float4*>(
            &A[(size_t)row * K + k0 + k4]);
        bf16x4 w;
        w[0] = (__bf16)v.x; w[1] = (__bf16)v.y;
        w[2] = (__bf16)v.z; w[3] = (__bf16)v.w;
        *reinterpret_cast<bf16x4*>(&Ab[row * 64 + (k4 ^ ((row & 7) << 3))]) = w;
      }
    }
    __syncthreads();
#pragma unroll
    for (int kk = 0; kk < 64; kk += 32) {
      bf16x8 bfr[2];
#pragma unroll
      for (int jf = 0; jf < 2; ++jf) {
        const float* wq = W + (size_t)(k0 + kk + koct) * 4096 + n_base + jf * 16;
        bf16x8 bv;
#pragma unroll
        for (int j = 0; j < 8; ++j) bv[j] = (__bf16)wq[(size_t)j * 4096];
        bfr[jf] = bv;
      }
      int kl = kk + koct;
#pragma unroll
      for (int i = 0; i < 4; ++i) {
        int t = wr * 64 + i * 16 + (lane & 15);
        bf16x8 af = *reinterpret_cast<const bf16x8*>(
            &Ab[t * 64 + (kl ^ ((t & 7) << 3))]);
        acc[i][0] = __builtin_amdgcn_mfma_f32_16x16x32_bf16(af, bfr[0], acc[i][0], 0, 0, 0);
        acc[i][1] = __builtin_amdgcn_mfma_f32_16x16x32_bf16(af, bfr[1], acc[i][1], 0, 0, 0);
      }
    }
  }

  float* outp = parts + (size_t)zp * (128 * 4096);
#pragma unroll
  for (int i = 0; i < 4; ++i)
#pragma unroll
    for (int jf = 0; jf < 2; ++jf)
#pragma unroll
      for (int r = 0; r < 4; ++r) {
        int row = wr * 64 + i * 16 + ((lane >> 4) << 2) + r;
        int col = cb * 64 + wc * 32 + jf * 16 + (lane & 15);
        outp[(size_t)row * 4096 + col] = acc[i][jf][r];
      }
}

// ---------------------------------------------------------------------------
// 6) LSTM gates: z = sum of 8 parts + bias
// ---------------------------------------------------------------------------
__global__ __launch_bounds__(256) void gate_kernel(
    const float* __restrict__ parts, const float* __restrict__ bias,
    const float* __restrict__ c_prev, float* __restrict__ h_out,
    float* __restrict__ c_out) {
  int idx = blockIdx.x * 256 + threadIdx.x;
  int b = idx >> 10, j = idx & 1023;
  float zv[4];
  for (int g = 0; g < 4; ++g) {
    size_t off = (size_t)b * 4096 + g * 1024 + j;
    float s = bias[g * 1024 + j];
    for (int p = 0; p < 8; ++p) s += parts[(size_t)p * (128 * 4096) + off];
    zv[g] = s;
  }
  float ig = sigmoidf(zv[0]);
  float fg = sigmoidf(zv[1]);
  float gg = tanhf(zv[2]);
  float og = sigmoidf(zv[3]);
  float cn = fg * c_prev[idx] + ig * gg;
  float hn = og * tanhf(cn);
  h_out[idx] = hn;
  c_out[idx] = cn;
}

// ---------------------------------------------------------------------------
// 7) Projection: reads h2n (d_out) + attention slice of rnn_in; 3-way k-split.
// ---------------------------------------------------------------------------
__global__ __launch_bounds__(256) void proj_kernel(
    const float* __restrict__ h2n, const float* __restrict__ rnn_in,
    const float* __restrict__ Wp, const float* __restrict__ bp,
    float* __restrict__ mel, float* __restrict__ stops) {
  int b = blockIdx.x;
  int tid = threadIdx.x;
  __shared__ float row[1536];
  __shared__ float red[3][81];
  for (int i = tid; i < 1536; i += 256)
    row[i] = (i < 1024) ? h2n[(size_t)b * 1024 + i]
                        : rnn_in[(size_t)b * 768 + 256 + (i - 1024)];
  __syncthreads();
  if (tid < 243) {
    int o = tid % 81, part = tid / 81;
    float s = 0.0f;
    int m0 = part * 512;
    for (int m = m0; m < m0 + 512; ++m) s = fmaf(row[m], Wp[m * 81 + o], s);
    red[part][o] = s;
  }
  __syncthreads();
  if (tid < 81) {
    float s = bp[tid] + red[0][tid] + red[1][tid] + red[2][tid];
    if (tid < 80) mel[b * 80 + tid] = s;
    else stops[b] = s;
  }
}

// ---------------------------------------------------------------------------
extern "C" void kernel_launch(void* const* d_in, const int* in_sizes, int n_in,
                              void* d_out, int out_size, void* d_ws,
                              size_t ws_size, hipStream_t stream) {
  const float* enc  = (const float*)d_in[0];
  const float* mels = (const float*)d_in[1];
  const float* prev = (const float*)d_in[2];
  const float* h1   = (const float*)d_in[3];
  const float* c1   = (const float*)d_in[4];
  const float* h2   = (const float*)d_in[5];
  const float* c2   = (const float*)d_in[6];
  const float* Wp1  = (const float*)d_in[7];
  const float* bp1  = (const float*)d_in[8];
  const float* Wp2  = (const float*)d_in[9];
  const float* bp2  = (const float*)d_in[10];
  const float* Wq   = (const float*)d_in[11];
  const float* Wk   = (const float*)d_in[12];
  const float* bk   = (const float*)d_in[13];
  const float* va   = (const float*)d_in[14];
  const float* bsc  = (const float*)d_in[15];
  const float* Wx1  = (const float*)d_in[16];
  const float* Wh1  = (const float*)d_in[17];
  const float* bl1  = (const float*)d_in[18];
  const float* Wx2  = (const float*)d_in[19];
  const float* Wh2  = (const float*)d_in[20];
  const float* bl2  = (const float*)d_in[21];
  const float* Wpj  = (const float*)d_in[22];
  const float* bpj  = (const float*)d_in[23];

  float* out = (float*)d_out;
  float* mel    = out;            // 128*80
  float* stops  = out + 10240;    // 128
  float* aligno = out + 10368;    // 128*512
  float* h1n    = out + 75904;    // 128*1024
  float* c1n    = out + 206976;
  float* h2n    = out + 338048;
  float* c2n    = out + 469120;

  float* ws = (float*)d_ws;
  float* q_ws   = ws;              // 16384
  float* sc_ws  = ws + 16384;      // 65536
  float* rnn_in = ws + 81920;      // 128*768
  float* parts  = ws + 180224;     // 8 * 524288 = 4,194,304
  int*   flag   = (int*)(ws + 4374528);  // 128 ints
  // WkT (bf16, 128KB) aliases head of `parts` — consumed before zgemm runs.
  __bf16* WkT = (__bf16*)parts;

  hipLaunchKernelGGL(prenet_kernel, dim3(192), dim3(256), 0, stream,
                     mels, Wp1, bp1, Wp2, bp2, Wq, Wk, WkT, rnn_in, q_ws);
  // score t < 256 (always full work), 512 blocks
  hipLaunchKernelGGL(score64_kernel, dim3(4, 128), dim3(256), 0, stream,
                     enc, WkT, bk, q_ws, va, bsc, sc_ws, 0, (const int*)nullptr);
  hipLaunchKernelGGL(cpflag_kernel, dim3(128), dim3(256), 0, stream,
                     sc_ws, flag);
  // score t >= 256 (pure-return for flagged b)
  hipLaunchKernelGGL(score64_kernel, dim3(4, 128), dim3(256), 0, stream,
                     enc, WkT, bk, q_ws, va, bsc, sc_ws, 256, (const int*)flag);
  hipLaunchKernelGGL(scan_kernel, dim3(128), dim3(512), 0, stream,
                     sc_ws, prev, flag, aligno);
  hipLaunchKernelGGL(att_part_kernel, dim3(8, 2, 128), dim3(256), 0, stream,
                     aligno, enc, rnn_in);
  hipLaunchKernelGGL(zgemm_mfma_kernel, dim3(64, 8), dim3(256), 0, stream,
                     rnn_in, 768, Wx1, h1, 1024, Wh1, parts);
  hipLaunchKernelGGL(gate_kernel, dim3(512), dim3(256), 0, stream,
                     parts, bl1, c1, h1n, c1n);
  hipLaunchKernelGGL(zgemm_mfma_kernel, dim3(64, 8), dim3(256), 0, stream,
                     h1n, 1024, Wx2, h2, 1024, Wh2, parts);
  hipLaunchKernelGGL(gate_kernel, dim3(512), dim3(256), 0, stream,
                     parts, bl2, c2, h2n, c2n);
  hipLaunchKernelGGL(proj_kernel, dim3(128), dim3(256), 0, stream,
                     h2n, rnn_in, Wpj, bpj, mel, stops);
}